// Round 5
// baseline (205.780 us; speedup 1.0000x reference)
//
#include <hip/hip_runtime.h>
#include <hip/hip_bf16.h>
#include <stdint.h>

typedef float f32x4 __attribute__((ext_vector_type(4)));
typedef __bf16 bf16x8 __attribute__((ext_vector_type(8)));
typedef unsigned short u16;

#define MFMA16(a, b, c) __builtin_amdgcn_mfma_f32_16x16x32_bf16((a), (b), (c), 0, 0, 0)

__device__ __forceinline__ u16 f2bf(float f) {
  union { float f; uint32_t u; } v; v.f = f;
  uint32_t u = v.u;
  return (u16)((u + 0x7fffu + ((u >> 16) & 1u)) >> 16);
}
__device__ __forceinline__ float bf2f(u16 h) {
  union { uint32_t u; float f; } v; v.u = ((uint32_t)h) << 16;
  return v.f;
}

// ---------------- kernel 0: weights -> bf16 transposed [c][k] -----------------
__global__ void prep_weights_kernel(const float* __restrict__ Wq, const float* __restrict__ Wk,
                                    const float* __restrict__ Wv, const float* __restrict__ Wp,
                                    u16* __restrict__ Wt) {
  int w = blockIdx.x;
  const float* W = (w == 0) ? Wq : (w == 1) ? Wk : (w == 2) ? Wv : Wp;
  int t = blockIdx.y * 256 + threadIdx.x;  // 0..16383
  int c = t >> 7, k = t & 127;
  Wt[(w * 128 + c) * 128 + k] = f2bf(W[k * 128 + c]);
}

// ---------------- kernel 1: QKV projection -----------------------------------
// x viewed as [102400][128] fp32.  Outputs: Qb,Kb [m][d] bf16; Vt [n][d][t] bf16.
__global__ __launch_bounds__(512) void qkv_kernel(
    const float* __restrict__ x, const u16* __restrict__ Wt,
    const float* __restrict__ bq, const float* __restrict__ bk, const float* __restrict__ bv,
    u16* __restrict__ Qb, u16* __restrict__ Kb, u16* __restrict__ Vt) {
  __shared__ u16 x_lds[128][136];
  __shared__ u16 w_lds[128][136];
  const int tid = threadIdx.x;
  const int m0 = blockIdx.x * 128;
  {  // stage x tile (fp32 -> bf16), coalesced
    int row = tid >> 2, cp = (tid & 3) * 32;
    const float* src = x + (size_t)(m0 + row) * 128 + cp;
    u16* dst = &x_lds[row][cp];
#pragma unroll
    for (int j = 0; j < 8; ++j) {
      float4 f = *(const float4*)(src + j * 4);
      dst[j * 4 + 0] = f2bf(f.x); dst[j * 4 + 1] = f2bf(f.y);
      dst[j * 4 + 2] = f2bf(f.z); dst[j * 4 + 3] = f2bf(f.w);
    }
  }
  __syncthreads();
  const int l = tid & 63, wv = tid >> 6, l15 = l & 15, l4 = l >> 4;
  const int rb = wv * 16;
  bf16x8 af[4];
#pragma unroll
  for (int ks = 0; ks < 4; ++ks)
    af[ks] = *(const bf16x8*)&x_lds[rb + l15][ks * 32 + l4 * 8];

#pragma unroll 1
  for (int o = 0; o < 3; ++o) {
    __syncthreads();
    {  // stage weight o into LDS
      int row = tid >> 2, cp = (tid & 3) * 32;
      const u16* src = Wt + (size_t)(o * 128 + row) * 128 + cp;
      u16* dst = &w_lds[row][cp];
#pragma unroll
      for (int j = 0; j < 4; ++j)
        *(bf16x8*)(dst + j * 8) = *(const bf16x8*)(src + j * 8);
    }
    __syncthreads();
    f32x4 acc[8];
#pragma unroll
    for (int ct = 0; ct < 8; ++ct) acc[ct] = f32x4{0.f, 0.f, 0.f, 0.f};
#pragma unroll
    for (int ct = 0; ct < 8; ++ct)
#pragma unroll
      for (int ks = 0; ks < 4; ++ks) {
        bf16x8 bfr = *(const bf16x8*)&w_lds[ct * 16 + l15][ks * 32 + l4 * 8];
        acc[ct] = MFMA16(af[ks], bfr, acc[ct]);
      }
    const float* bptr = (o == 0) ? bq : (o == 1) ? bk : bv;
    float bias[8];
#pragma unroll
    for (int ct = 0; ct < 8; ++ct) bias[ct] = bptr[ct * 16 + l15];
    __syncthreads();
    if (o < 2) {  // store rows [tt][d]
#pragma unroll
      for (int ct = 0; ct < 8; ++ct)
#pragma unroll
        for (int rg = 0; rg < 4; ++rg)
          w_lds[rb + 4 * l4 + rg][ct * 16 + l15] = f2bf(acc[ct][rg] + bias[ct]);
    } else {      // V: store transposed [d][tt]
#pragma unroll
      for (int ct = 0; ct < 8; ++ct)
#pragma unroll
        for (int rg = 0; rg < 4; ++rg)
          w_lds[ct * 16 + l15][rb + 4 * l4 + rg] = f2bf(acc[ct][rg] + bias[ct]);
    }
    __syncthreads();
    {  // coalesced copy-out
      int row = tid >> 2, cp = (tid & 3) * 32;
      u16* dst;
      if (o == 0)      dst = Qb + (size_t)(m0 + row) * 128 + cp;
      else if (o == 1) dst = Kb + (size_t)(m0 + row) * 128 + cp;
      else {
        int n = m0 >> 8, tb = m0 & 255;
        dst = Vt + ((size_t)(n * 128 + row)) * 256 + tb + cp;
      }
      const u16* src = &w_lds[row][cp];
#pragma unroll
      for (int j = 0; j < 4; ++j)
        *(bf16x8*)(dst + j * 8) = *(const bf16x8*)(src + j * 8);
    }
  }
}

// ---------------- kernel 2: per-n mean of V ----------------------------------
__global__ void vmean_kernel(const u16* __restrict__ Vt, float* __restrict__ Vmean) {
  int n = blockIdx.x, d = threadIdx.x;
  const u16* row = Vt + ((size_t)(n * 128 + d)) * 256;
  float s = 0.f;
#pragma unroll 4
  for (int j = 0; j < 32; ++j) {
    uint4 u = *(const uint4*)(row + j * 8);
    uint32_t w0 = u.x, w1 = u.y, w2 = u.z, w3 = u.w;
    s += bf2f((u16)(w0 & 0xffff)) + bf2f((u16)(w0 >> 16));
    s += bf2f((u16)(w1 & 0xffff)) + bf2f((u16)(w1 >> 16));
    s += bf2f((u16)(w2 & 0xffff)) + bf2f((u16)(w2 >> 16));
    s += bf2f((u16)(w3 & 0xffff)) + bf2f((u16)(w3 >> 16));
  }
  Vmean[n * 128 + d] = s * (1.f / 256.f);
}

// ---------------- kernel 3: high-TLP flash attention (no K/V staging) --------
// 1600 blocks x 256 threads (4 waves; wave = 16 q-rows). K/V/Wp fragments are
// read directly from global (L2/L3-hot; each frag load = 16 rows x 64B full
// lines). LDS: rel table + per-wave 16x40 P/ctx repack slice. One barrier.
__global__ __launch_bounds__(256, 4) void attn3_kernel(
    const u16* __restrict__ Qb, const u16* __restrict__ Kb, const u16* __restrict__ Vt,
    const u16* __restrict__ Wpt,
    const float* __restrict__ x, const int* __restrict__ mask,
    const float* __restrict__ rel, const float* __restrict__ bp,
    const float* __restrict__ ln_g, const float* __restrict__ ln_b,
    const float* __restrict__ Vmean, float* __restrict__ out) {
  __shared__ u16 P_lds[4][16][40];   // per-wave P / ctx repack slices (5120 B)
  __shared__ float rel_lds[511];     // 2044 B
  const int tid = threadIdx.x;
  // XCD-aware swizzle (1600 % 8 == 0 -> bijective): 4 q-tiles of one n stay on
  // one XCD so its K/V (192 KB) get L2 locality.
  const int bid = blockIdx.x;
  const int swz = (bid & 7) * 200 + (bid >> 3);
  const int n = swz >> 2, qt = swz & 3;
  const int bb = n / 100, rr = n - bb * 100;
  const int* mrow = mask + bb * 256;
  for (int i = tid; i < 511; i += 256) rel_lds[i] = rel[i];
  __syncthreads();  // rel_lds ready; no further block syncs

  const int l = tid & 63, wv = tid >> 6, l15 = l & 15, l4 = l >> 4;
  const int tt0 = qt * 64 + wv * 16;   // this wave's 16 q-rows
  bf16x8 qa[4];
  {
    const u16* qrow = Qb + ((size_t)(n * 256 + tt0 + l15)) * 128;
#pragma unroll
    for (int ks = 0; ks < 4; ++ks)
      qa[ks] = *(const bf16x8*)(qrow + ks * 32 + l4 * 8);
  }
  int ttg[4], qm[4];
#pragma unroll
  for (int rg = 0; rg < 4; ++rg) { ttg[rg] = tt0 + 4 * l4 + rg; qm[rg] = mrow[ttg[rg]]; }
  float mi[4], li[4]; f32x4 cacc[8];
#pragma unroll
  for (int rg = 0; rg < 4; ++rg) { mi[rg] = -40.f; li[rg] = 0.f; }
#pragma unroll
  for (int ct = 0; ct < 8; ++ct) cacc[ct] = f32x4{0.f, 0.f, 0.f, 0.f};

  const u16* Kn = Kb + (size_t)n * 256 * 128;
  const u16* Vn = Vt + (size_t)n * 128 * 256;
  const int nkv = qt + 1;
  for (int kv = 0; kv < nkv; ++kv) {
    const int s0 = kv * 64;
    f32x4 sacc[4];
#pragma unroll
    for (int ct = 0; ct < 4; ++ct) sacc[ct] = f32x4{0.f, 0.f, 0.f, 0.f};
#pragma unroll
    for (int ct = 0; ct < 4; ++ct)
#pragma unroll
      for (int ks = 0; ks < 4; ++ks) {
        bf16x8 bfr = *(const bf16x8*)(Kn + (size_t)(s0 + ct * 16 + l15) * 128 + ks * 32 + l4 * 8);
        sacc[ct] = MFMA16(qa[ks], bfr, sacc[ct]);
      }
    int km[4];
#pragma unroll
    for (int ct = 0; ct < 4; ++ct) km[ct] = mrow[s0 + ct * 16 + l15];
    const float scale = 0.088388347648318447f;  // 1/sqrt(128)
    float p[4][4], tmax[4];
#pragma unroll
    for (int rg = 0; rg < 4; ++rg) tmax[rg] = -3.0e38f;
#pragma unroll
    for (int ct = 0; ct < 4; ++ct) {
      const int ss = s0 + ct * 16 + l15;
#pragma unroll
      for (int rg = 0; rg < 4; ++rg) {
        float sv = sacc[ct][rg] * scale;
        int idx = ttg[rg] - ss + 255;
        idx = idx < 0 ? 0 : (idx > 510 ? 510 : idx);
        sv += rel_lds[idx];
        bool msk = (ss > ttg[rg]) | (km[ct] == 0) | (qm[rg] == 0);
        sv = msk ? -1.0e9f : sv;
        p[ct][rg] = sv;
        tmax[rg] = fmaxf(tmax[rg], sv);
      }
    }
#pragma unroll
    for (int rg = 0; rg < 4; ++rg) {
      float t = tmax[rg];
#pragma unroll
      for (int off = 1; off < 16; off <<= 1) t = fmaxf(t, __shfl_xor(t, off));
      float mnew = fmaxf(mi[rg], t);
      float sc = __expf(mi[rg] - mnew);
      mi[rg] = mnew;
      float rs = 0.f;
#pragma unroll
      for (int ct = 0; ct < 4; ++ct) {
        float pv = __expf(p[ct][rg] - mnew);
        p[ct][rg] = pv; rs += pv;
      }
#pragma unroll
      for (int off = 1; off < 16; off <<= 1) rs += __shfl_xor(rs, off);
      li[rg] = li[rg] * sc + rs;
#pragma unroll
      for (int ct = 0; ct < 8; ++ct) cacc[ct][rg] *= sc;
    }
    // PV in two 32-key chunks through the per-wave P slice (wave-private)
#pragma unroll
    for (int c = 0; c < 2; ++c) {
#pragma unroll
      for (int c2 = 0; c2 < 2; ++c2)
#pragma unroll
        for (int rg = 0; rg < 4; ++rg)
          P_lds[wv][4 * l4 + rg][c2 * 16 + l15] = f2bf(p[2 * c + c2][rg]);
      bf16x8 pa = *(const bf16x8*)&P_lds[wv][l15][l4 * 8];
#pragma unroll
      for (int ct = 0; ct < 8; ++ct) {
        bf16x8 vb = *(const bf16x8*)(Vn + (size_t)(ct * 16 + l15) * 256 + s0 + c * 32 + l4 * 8);
        cacc[ct] = MFMA16(pa, vb, cacc[ct]);
      }
    }
  }
  // finalize ctx (query-masked rows -> mean of all V rows, matching reference)
  float vm[8];
#pragma unroll
  for (int ct = 0; ct < 8; ++ct) vm[ct] = Vmean[n * 128 + ct * 16 + l15];
  // ctx -> bf16 A-frags via per-wave slice, 4 column-quarters
  bf16x8 ca[4];
#pragma unroll
  for (int q = 0; q < 4; ++q) {
#pragma unroll
    for (int c2 = 0; c2 < 2; ++c2) {
      int ct = 2 * q + c2;
#pragma unroll
      for (int rg = 0; rg < 4; ++rg) {
        float cval = cacc[ct][rg] / li[rg];
        cval = (qm[rg] == 0) ? vm[ct] : cval;
        P_lds[wv][4 * l4 + rg][c2 * 16 + l15] = f2bf(cval);
      }
    }
    ca[q] = *(const bf16x8*)&P_lds[wv][l15][l4 * 8];
  }
  f32x4 oacc[8];
#pragma unroll
  for (int ct = 0; ct < 8; ++ct) oacc[ct] = f32x4{0.f, 0.f, 0.f, 0.f};
#pragma unroll
  for (int ct = 0; ct < 8; ++ct)
#pragma unroll
    for (int ks = 0; ks < 4; ++ks) {
      bf16x8 b = *(const bf16x8*)(Wpt + (size_t)(ct * 16 + l15) * 128 + ks * 32 + l4 * 8);
      oacc[ct] = MFMA16(ca[ks], b, oacc[ct]);
    }
  float bpv[8], gv[8], bt[8];
#pragma unroll
  for (int ct = 0; ct < 8; ++ct) {
    int d = ct * 16 + l15;
    bpv[ct] = bp[d]; gv[ct] = ln_g[d]; bt[ct] = ln_b[d];
  }
#pragma unroll
  for (int rg = 0; rg < 4; ++rg) {
    const int tg = ttg[rg];
    const float* xrow = x + ((size_t)(n * 256 + tg)) * 128;
    float yv[8], sum = 0.f, sq = 0.f;
#pragma unroll
    for (int ct = 0; ct < 8; ++ct) {
      float v = oacc[ct][rg] + bpv[ct] + xrow[ct * 16 + l15];
      yv[ct] = v; sum += v; sq += v * v;
    }
#pragma unroll
    for (int off = 1; off < 16; off <<= 1) { sum += __shfl_xor(sum, off); sq += __shfl_xor(sq, off); }
    float mean = sum * (1.f / 128.f);
    float var = sq * (1.f / 128.f) - mean * mean;
    float rstd = rsqrtf(var + 1e-5f);
    float* orow = out + (((size_t)(bb * 256 + tg)) * 100 + rr) * 128;
#pragma unroll
    for (int ct = 0; ct < 8; ++ct)
      orow[ct * 16 + l15] = (yv[ct] - mean) * rstd * gv[ct] + bt[ct];
  }
}

extern "C" void kernel_launch(void* const* d_in, const int* in_sizes, int n_in,
                              void* d_out, int out_size, void* d_ws, size_t ws_size,
                              hipStream_t stream) {
  const float* x    = (const float*)d_in[0];
  const int*   mask = (const int*)d_in[1];
  const float* Wq   = (const float*)d_in[2];
  const float* bq   = (const float*)d_in[3];
  const float* Wk   = (const float*)d_in[4];
  const float* bk   = (const float*)d_in[5];
  const float* Wv   = (const float*)d_in[6];
  const float* bv   = (const float*)d_in[7];
  const float* Wp   = (const float*)d_in[8];
  const float* bp   = (const float*)d_in[9];
  const float* ln_g = (const float*)d_in[10];
  const float* ln_b = (const float*)d_in[11];
  const float* rel  = (const float*)d_in[12];
  float* out = (float*)d_out;
  char* ws = (char*)d_ws;
  u16* Qb = (u16*)(ws);                       // 102400*128 bf16
  u16* Kb = (u16*)(ws + 26214400);            // 102400*128 bf16
  u16* Vt = (u16*)(ws + 52428800);            // [400][128][256] bf16
  u16* Wt = (u16*)(ws + 78643200);            // [4][128][128] bf16 transposed
  float* Vmean = (float*)(ws + 78643200 + 131072);  // [400][128] fp32

  hipLaunchKernelGGL(prep_weights_kernel, dim3(4, 64), dim3(256), 0, stream, Wq, Wk, Wv, Wp, Wt);
  hipLaunchKernelGGL(qkv_kernel, dim3(800), dim3(512), 0, stream, x, Wt, bq, bk, bv, Qb, Kb, Vt);
  hipLaunchKernelGGL(vmean_kernel, dim3(400), dim3(128), 0, stream, Vt, Vmean);
  hipLaunchKernelGGL(attn3_kernel, dim3(1600), dim3(256), 0, stream,
                     Qb, Kb, Vt, Wt + 3 * 16384, x, mask, rel, bp, ln_g, ln_b, Vmean, out);
}

// Round 6
// 129.410 us; speedup vs baseline: 1.5901x; 1.5901x over previous
//
#include <hip/hip_runtime.h>
#include <hip/hip_bf16.h>
#include <stdint.h>

typedef float f32x4 __attribute__((ext_vector_type(4)));
typedef __bf16 bf16x8 __attribute__((ext_vector_type(8)));
typedef unsigned short u16;

#define MFMA16(a, b, c) __builtin_amdgcn_mfma_f32_16x16x32_bf16((a), (b), (c), 0, 0, 0)

__device__ __forceinline__ u16 f2bf(float f) {
  union { float f; uint32_t u; } v; v.f = f;
  uint32_t u = v.u;
  return (u16)((u + 0x7fffu + ((u >> 16) & 1u)) >> 16);
}
__device__ __forceinline__ float bf2f(u16 h) {
  union { uint32_t u; float f; } v; v.u = ((uint32_t)h) << 16;
  return v.f;
}

// ---------------- kernel 0: weights -> bf16 transposed [c][k] -----------------
__global__ void prep_weights_kernel(const float* __restrict__ Wq, const float* __restrict__ Wk,
                                    const float* __restrict__ Wv, const float* __restrict__ Wp,
                                    u16* __restrict__ Wt) {
  int w = blockIdx.x;
  const float* W = (w == 0) ? Wq : (w == 1) ? Wk : (w == 2) ? Wv : Wp;
  int t = blockIdx.y * 256 + threadIdx.x;  // 0..16383
  int c = t >> 7, k = t & 127;
  Wt[(w * 128 + c) * 128 + k] = f2bf(W[k * 128 + c]);
}

// ---------------- kernel 1: QKV projection -----------------------------------
// x viewed as [102400][128] fp32.  Outputs: Qb,Kb [m][d] bf16; Vt [n][d][t] bf16.
__global__ __launch_bounds__(512) void qkv_kernel(
    const float* __restrict__ x, const u16* __restrict__ Wt,
    const float* __restrict__ bq, const float* __restrict__ bk, const float* __restrict__ bv,
    u16* __restrict__ Qb, u16* __restrict__ Kb, u16* __restrict__ Vt) {
  __shared__ u16 x_lds[128][136];
  __shared__ u16 w_lds[128][136];
  const int tid = threadIdx.x;
  const int m0 = blockIdx.x * 128;
  {  // stage x tile (fp32 -> bf16), coalesced
    int row = tid >> 2, cp = (tid & 3) * 32;
    const float* src = x + (size_t)(m0 + row) * 128 + cp;
    u16* dst = &x_lds[row][cp];
#pragma unroll
    for (int j = 0; j < 8; ++j) {
      float4 f = *(const float4*)(src + j * 4);
      dst[j * 4 + 0] = f2bf(f.x); dst[j * 4 + 1] = f2bf(f.y);
      dst[j * 4 + 2] = f2bf(f.z); dst[j * 4 + 3] = f2bf(f.w);
    }
  }
  __syncthreads();
  const int l = tid & 63, wv = tid >> 6, l15 = l & 15, l4 = l >> 4;
  const int rb = wv * 16;
  bf16x8 af[4];
#pragma unroll
  for (int ks = 0; ks < 4; ++ks)
    af[ks] = *(const bf16x8*)&x_lds[rb + l15][ks * 32 + l4 * 8];

#pragma unroll 1
  for (int o = 0; o < 3; ++o) {
    __syncthreads();
    {  // stage weight o into LDS
      int row = tid >> 2, cp = (tid & 3) * 32;
      const u16* src = Wt + (size_t)(o * 128 + row) * 128 + cp;
      u16* dst = &w_lds[row][cp];
#pragma unroll
      for (int j = 0; j < 4; ++j)
        *(bf16x8*)(dst + j * 8) = *(const bf16x8*)(src + j * 8);
    }
    __syncthreads();
    f32x4 acc[8];
#pragma unroll
    for (int ct = 0; ct < 8; ++ct) acc[ct] = f32x4{0.f, 0.f, 0.f, 0.f};
#pragma unroll
    for (int ct = 0; ct < 8; ++ct)
#pragma unroll
      for (int ks = 0; ks < 4; ++ks) {
        bf16x8 bfr = *(const bf16x8*)&w_lds[ct * 16 + l15][ks * 32 + l4 * 8];
        acc[ct] = MFMA16(af[ks], bfr, acc[ct]);
      }
    const float* bptr = (o == 0) ? bq : (o == 1) ? bk : bv;
    float bias[8];
#pragma unroll
    for (int ct = 0; ct < 8; ++ct) bias[ct] = bptr[ct * 16 + l15];
    __syncthreads();
    if (o < 2) {  // store rows [tt][d]
#pragma unroll
      for (int ct = 0; ct < 8; ++ct)
#pragma unroll
        for (int rg = 0; rg < 4; ++rg)
          w_lds[rb + 4 * l4 + rg][ct * 16 + l15] = f2bf(acc[ct][rg] + bias[ct]);
    } else {      // V: store transposed [d][tt]
#pragma unroll
      for (int ct = 0; ct < 8; ++ct)
#pragma unroll
        for (int rg = 0; rg < 4; ++rg)
          w_lds[ct * 16 + l15][rb + 4 * l4 + rg] = f2bf(acc[ct][rg] + bias[ct]);
    }
    __syncthreads();
    {  // coalesced copy-out
      int row = tid >> 2, cp = (tid & 3) * 32;
      u16* dst;
      if (o == 0)      dst = Qb + (size_t)(m0 + row) * 128 + cp;
      else if (o == 1) dst = Kb + (size_t)(m0 + row) * 128 + cp;
      else {
        int n = m0 >> 8, tb = m0 & 255;
        dst = Vt + ((size_t)(n * 128 + row)) * 256 + tb + cp;
      }
      const u16* src = &w_lds[row][cp];
#pragma unroll
      for (int j = 0; j < 4; ++j)
        *(bf16x8*)(dst + j * 8) = *(const bf16x8*)(src + j * 8);
    }
  }
}

// ---------------- kernel 2: per-n mean of V ----------------------------------
__global__ void vmean_kernel(const u16* __restrict__ Vt, float* __restrict__ Vmean) {
  int n = blockIdx.x, d = threadIdx.x;
  const u16* row = Vt + ((size_t)(n * 128 + d)) * 256;
  float s = 0.f;
#pragma unroll 4
  for (int j = 0; j < 32; ++j) {
    uint4 u = *(const uint4*)(row + j * 8);
    uint32_t w0 = u.x, w1 = u.y, w2 = u.z, w3 = u.w;
    s += bf2f((u16)(w0 & 0xffff)) + bf2f((u16)(w0 >> 16));
    s += bf2f((u16)(w1 & 0xffff)) + bf2f((u16)(w1 >> 16));
    s += bf2f((u16)(w2 & 0xffff)) + bf2f((u16)(w2 >> 16));
    s += bf2f((u16)(w3 & 0xffff)) + bf2f((u16)(w3 >> 16));
  }
  Vmean[n * 128 + d] = s * (1.f / 256.f);
}

// ---------------- kernel 3: block-per-n, 16-wave flash attention -------------
// 400 blocks x 1024 threads (16 waves, 4/SIMD). K and V^T staged once in LDS;
// each wave owns 16 q-rows, causal kv loop fully LDS-resident, no block syncs
// after staging. Per-SIMD wave set {1,2,3,4} kv-tiles -> balanced (10 each).
__global__ __launch_bounds__(1024, 4) void attn4_kernel(
    const u16* __restrict__ Qb, const u16* __restrict__ Kb, const u16* __restrict__ Vt,
    const u16* __restrict__ Wpt,
    const float* __restrict__ x, const int* __restrict__ mask,
    const float* __restrict__ rel, const float* __restrict__ bp,
    const float* __restrict__ ln_g, const float* __restrict__ ln_b,
    const float* __restrict__ Vmean, float* __restrict__ out) {
  __shared__ u16 K_lds[256][136];       // 69632 B
  __shared__ u16 V_lds[128][264];       // 67584 B  (V^T: [d][s])
  __shared__ u16 P_lds[16][16][40];     // 20480 B  per-wave P / ctx repack slices
  __shared__ float rel_lds[511];        //  2044 B  -> total 159740 B
  const int tid = threadIdx.x;
  const int n = blockIdx.x;
  const int bb = n / 100, rr = n - bb * 100;
  const int* mrow = mask + bb * 256;
  if (tid < 511) rel_lds[tid] = rel[tid];
  {  // stage K [256][128] -> K_lds
    int row = tid >> 2, cp = (tid & 3) * 32;
    const u16* src = Kb + ((size_t)(n * 256 + row)) * 128 + cp;
    u16* dst = &K_lds[row][cp];
#pragma unroll
    for (int j = 0; j < 4; ++j) *(bf16x8*)(dst + j * 8) = *(const bf16x8*)(src + j * 8);
  }
  {  // stage V^T [128][256] -> V_lds
    int row = tid >> 3, cq = (tid & 7) * 32;
    const u16* src = Vt + ((size_t)(n * 128 + row)) * 256 + cq;
    u16* dst = &V_lds[row][cq];
#pragma unroll
    for (int j = 0; j < 4; ++j) *(bf16x8*)(dst + j * 8) = *(const bf16x8*)(src + j * 8);
  }
  const int l = tid & 63, wv = tid >> 6, l15 = l & 15, l4 = l >> 4;
  const int tt0 = wv * 16;               // this wave's 16 q-rows
  bf16x8 qa[4];
  {
    const u16* qrow = Qb + ((size_t)(n * 256 + tt0 + l15)) * 128;
#pragma unroll
    for (int ks = 0; ks < 4; ++ks)
      qa[ks] = *(const bf16x8*)(qrow + ks * 32 + l4 * 8);
  }
  int ttg[4], qm[4];
#pragma unroll
  for (int rg = 0; rg < 4; ++rg) { ttg[rg] = tt0 + 4 * l4 + rg; qm[rg] = mrow[ttg[rg]]; }
  float mi[4], li[4]; f32x4 cacc[8];
#pragma unroll
  for (int rg = 0; rg < 4; ++rg) { mi[rg] = -40.f; li[rg] = 0.f; }
#pragma unroll
  for (int ct = 0; ct < 8; ++ct) cacc[ct] = f32x4{0.f, 0.f, 0.f, 0.f};
  __syncthreads();  // staging complete; no more block syncs

  const int nkv = (wv >> 2) + 1;  // causal tiles for rows < 16*(wv+1)
  for (int kv = 0; kv < nkv; ++kv) {
    const int s0 = kv * 64;
    f32x4 sacc[4];
#pragma unroll
    for (int ct = 0; ct < 4; ++ct) sacc[ct] = f32x4{0.f, 0.f, 0.f, 0.f};
#pragma unroll
    for (int ct = 0; ct < 4; ++ct)
#pragma unroll
      for (int ks = 0; ks < 4; ++ks) {
        bf16x8 bfr = *(const bf16x8*)&K_lds[s0 + ct * 16 + l15][ks * 32 + l4 * 8];
        sacc[ct] = MFMA16(qa[ks], bfr, sacc[ct]);
      }
    int km[4];
#pragma unroll
    for (int ct = 0; ct < 4; ++ct) km[ct] = mrow[s0 + ct * 16 + l15];
    const float scale = 0.088388347648318447f;  // 1/sqrt(128)
    float p[4][4], tmax[4];
#pragma unroll
    for (int rg = 0; rg < 4; ++rg) tmax[rg] = -3.0e38f;
#pragma unroll
    for (int ct = 0; ct < 4; ++ct) {
      const int ss = s0 + ct * 16 + l15;
#pragma unroll
      for (int rg = 0; rg < 4; ++rg) {
        float sv = sacc[ct][rg] * scale;
        int idx = ttg[rg] - ss + 255;
        idx = idx < 0 ? 0 : (idx > 510 ? 510 : idx);
        sv += rel_lds[idx];
        bool msk = (ss > ttg[rg]) | (km[ct] == 0) | (qm[rg] == 0);
        sv = msk ? -1.0e9f : sv;
        p[ct][rg] = sv;
        tmax[rg] = fmaxf(tmax[rg], sv);
      }
    }
#pragma unroll
    for (int rg = 0; rg < 4; ++rg) {
      float t = tmax[rg];
#pragma unroll
      for (int off = 1; off < 16; off <<= 1) t = fmaxf(t, __shfl_xor(t, off));
      float mnew = fmaxf(mi[rg], t);
      float sc = __expf(mi[rg] - mnew);
      mi[rg] = mnew;
      float rs = 0.f;
#pragma unroll
      for (int ct = 0; ct < 4; ++ct) {
        float pv = __expf(p[ct][rg] - mnew);
        p[ct][rg] = pv; rs += pv;
      }
#pragma unroll
      for (int off = 1; off < 16; off <<= 1) rs += __shfl_xor(rs, off);
      li[rg] = li[rg] * sc + rs;
#pragma unroll
      for (int ct = 0; ct < 8; ++ct) cacc[ct][rg] *= sc;
    }
    // PV in two 32-key chunks through the per-wave P slice (wave-private)
#pragma unroll
    for (int c = 0; c < 2; ++c) {
#pragma unroll
      for (int c2 = 0; c2 < 2; ++c2)
#pragma unroll
        for (int rg = 0; rg < 4; ++rg)
          P_lds[wv][4 * l4 + rg][c2 * 16 + l15] = f2bf(p[2 * c + c2][rg]);
      bf16x8 pa = *(const bf16x8*)&P_lds[wv][l15][l4 * 8];
#pragma unroll
      for (int ct = 0; ct < 8; ++ct) {
        bf16x8 vb = *(const bf16x8*)&V_lds[ct * 16 + l15][s0 + c * 32 + l4 * 8];
        cacc[ct] = MFMA16(pa, vb, cacc[ct]);
      }
    }
  }
  // finalize ctx (query-masked rows -> mean of all V rows, matching reference)
  float vm[8];
#pragma unroll
  for (int ct = 0; ct < 8; ++ct) vm[ct] = Vmean[n * 128 + ct * 16 + l15];
  // ctx -> bf16 A-frags via per-wave slice, 4 column-quarters
  bf16x8 ca[4];
#pragma unroll
  for (int q = 0; q < 4; ++q) {
#pragma unroll
    for (int c2 = 0; c2 < 2; ++c2) {
      int ct = 2 * q + c2;
#pragma unroll
      for (int rg = 0; rg < 4; ++rg) {
        float cval = cacc[ct][rg] / li[rg];
        cval = (qm[rg] == 0) ? vm[ct] : cval;
        P_lds[wv][4 * l4 + rg][c2 * 16 + l15] = f2bf(cval);
      }
    }
    ca[q] = *(const bf16x8*)&P_lds[wv][l15][l4 * 8];
  }
  f32x4 oacc[8];
#pragma unroll
  for (int ct = 0; ct < 8; ++ct) oacc[ct] = f32x4{0.f, 0.f, 0.f, 0.f};
#pragma unroll
  for (int ct = 0; ct < 8; ++ct)
#pragma unroll
    for (int ks = 0; ks < 4; ++ks) {
      bf16x8 b = *(const bf16x8*)(Wpt + (size_t)(ct * 16 + l15) * 128 + ks * 32 + l4 * 8);
      oacc[ct] = MFMA16(ca[ks], b, oacc[ct]);
    }
  float bpv[8], gv[8], bt[8];
#pragma unroll
  for (int ct = 0; ct < 8; ++ct) {
    int d = ct * 16 + l15;
    bpv[ct] = bp[d]; gv[ct] = ln_g[d]; bt[ct] = ln_b[d];
  }
#pragma unroll
  for (int rg = 0; rg < 4; ++rg) {
    const int tg = ttg[rg];
    const float* xrow = x + ((size_t)(n * 256 + tg)) * 128;
    float yv[8], sum = 0.f, sq = 0.f;
#pragma unroll
    for (int ct = 0; ct < 8; ++ct) {
      float v = oacc[ct][rg] + bpv[ct] + xrow[ct * 16 + l15];
      yv[ct] = v; sum += v; sq += v * v;
    }
#pragma unroll
    for (int off = 1; off < 16; off <<= 1) { sum += __shfl_xor(sum, off); sq += __shfl_xor(sq, off); }
    float mean = sum * (1.f / 128.f);
    float var = sq * (1.f / 128.f) - mean * mean;
    float rstd = rsqrtf(var + 1e-5f);
    float* orow = out + (((size_t)(bb * 256 + tg)) * 100 + rr) * 128;
#pragma unroll
    for (int ct = 0; ct < 8; ++ct)
      orow[ct * 16 + l15] = (yv[ct] - mean) * rstd * gv[ct] + bt[ct];
  }
}

extern "C" void kernel_launch(void* const* d_in, const int* in_sizes, int n_in,
                              void* d_out, int out_size, void* d_ws, size_t ws_size,
                              hipStream_t stream) {
  const float* x    = (const float*)d_in[0];
  const int*   mask = (const int*)d_in[1];
  const float* Wq   = (const float*)d_in[2];
  const float* bq   = (const float*)d_in[3];
  const float* Wk   = (const float*)d_in[4];
  const float* bk   = (const float*)d_in[5];
  const float* Wv   = (const float*)d_in[6];
  const float* bv   = (const float*)d_in[7];
  const float* Wp   = (const float*)d_in[8];
  const float* bp   = (const float*)d_in[9];
  const float* ln_g = (const float*)d_in[10];
  const float* ln_b = (const float*)d_in[11];
  const float* rel  = (const float*)d_in[12];
  float* out = (float*)d_out;
  char* ws = (char*)d_ws;
  u16* Qb = (u16*)(ws);                       // 102400*128 bf16
  u16* Kb = (u16*)(ws + 26214400);            // 102400*128 bf16
  u16* Vt = (u16*)(ws + 52428800);            // [400][128][256] bf16
  u16* Wt = (u16*)(ws + 78643200);            // [4][128][128] bf16 transposed
  float* Vmean = (float*)(ws + 78643200 + 131072);  // [400][128] fp32

  hipLaunchKernelGGL(prep_weights_kernel, dim3(4, 64), dim3(256), 0, stream, Wq, Wk, Wv, Wp, Wt);
  hipLaunchKernelGGL(qkv_kernel, dim3(800), dim3(512), 0, stream, x, Wt, bq, bk, bv, Qb, Kb, Vt);
  hipLaunchKernelGGL(vmean_kernel, dim3(400), dim3(128), 0, stream, Vt, Vmean);
  hipLaunchKernelGGL(attn4_kernel, dim3(400), dim3(1024), 0, stream,
                     Qb, Kb, Vt, Wt + 3 * 16384, x, mask, rel, bp, ln_g, ln_b, Vmean, out);
}